// Round 19
// baseline (142.033 us; speedup 1.0000x reference)
//
#include <hip/hip_runtime.h>
#include <math.h>

#define NB 8
#define NT 32
#define NAG 50
#define MTASK 100
#define MTOP 10
#define NNB 10
#define LDIM 5
#define HDIM 512
#define INDIM 1610
#define KP1 1664            // INDIM padded to multiple of 64
#define NKT1 (KP1/32)       // 52 k-chunks
#define NKT2 (HDIM/32)      // 16
#define NROWS (NB*NT*NAG)   // 12800
#define NOUT (MTOP+1)       // 11
#define NTOPKB (NROWS/4)    // 3200 topk blocks
#define NPREPX (KP1/64 + HDIM/64)   // 34
#define NPREPB (NPREPX * (HDIM/64)) // 272 prep blocks

typedef float f32x4 __attribute__((ext_vector_type(4)));
typedef _Float16 f16;
typedef _Float16 f16x8 __attribute__((ext_vector_type(8)));

__device__ __forceinline__ void gload16(const void* g, void* l) {
    __builtin_amdgcn_global_load_lds(
        (__attribute__((address_space(1))) void*)(g),
        (__attribute__((address_space(3))) void*)(l), 16, 0, 0);
}

// A-side tiled layout (64-row blocks): elem (row, c) at
//   (rowblk64 * NKT*4 + octet)*512 + (row&63)*8 + (c&7),  octet = c>>3
// B-side tiled layout (64-col blocks): (colblk64 * NKT*4 + octet)*512 + (col&63)*8 + e.

// ---------------- merged: top-10 tasks (blocks 0..3199) + weight prep (3200..3471) ----
__global__ __launch_bounds__(256) void k_topk_prep(
    const float* __restrict__ beta, float* __restrict__ total_beta,
    int* __restrict__ tasks,
    const float* __restrict__ W1, const float* __restrict__ W2,
    f16* __restrict__ T1, f16* __restrict__ T2) {
    __shared__ float lds[64][65];
    if (blockIdx.x < NTOPKB) {
        // ---- topk: wave per row ----
        int wid = threadIdx.x >> 6, lane = threadIdx.x & 63;
        int row = blockIdx.x * 4 + wid;
        const float* bp = beta + (size_t)row * MTASK * LDIM;
        float v1, v2 = -INFINITY;
        {
            const float* p = bp + lane * LDIM;
            v1 = p[0] + p[1] + p[2] + p[3] + p[4];
            total_beta[(size_t)row * MTASK + lane] = v1;
        }
        if (lane + 64 < MTASK) {
            const float* p = bp + (lane + 64) * LDIM;
            v2 = p[0] + p[1] + p[2] + p[3] + p[4];
            total_beta[(size_t)row * MTASK + lane + 64] = v2;
        }
        for (int k = 0; k < MTOP; ++k) {
            float v; int idx;
            if (v1 >= v2) { v = v1; idx = lane; } else { v = v2; idx = lane + 64; }
            #pragma unroll
            for (int m = 1; m < 64; m <<= 1) {
                float vo = __shfl_xor(v, m, 64);
                int io = __shfl_xor(idx, m, 64);
                if (vo > v || (vo == v && io < idx)) { v = vo; idx = io; }
            }
            if (lane == 0) tasks[row * MTOP + k] = idx;
            if (idx == lane) v1 = -INFINITY;
            else if (idx == lane + 64) v2 = -INFINITY;
        }
    } else {
        // ---- weight prep: W[K][N] -> tiled fp16 (64-col blocks) ----
        int pb = blockIdx.x - NTOPKB;
        int bx = pb % NPREPX, n0 = (pb / NPREPX) * 64;
        const float* W; f16* T; int K, NKT, kp0;
        if (bx < KP1 / 64) { W = W1; T = T1; K = INDIM; NKT = NKT1; kp0 = bx * 64; }
        else               { W = W2; T = T2; K = HDIM;  NKT = NKT2; kp0 = (bx - KP1 / 64) * 64; }
        int t = threadIdx.x;
        int cc = t & 63, r0 = t >> 6;
        #pragma unroll
        for (int i = 0; i < 16; ++i) {
            int rr = r0 + i * 4;
            int kp = kp0 + rr;
            lds[rr][cc] = (kp < K) ? W[(size_t)kp * HDIM + n0 + cc] : 0.f;
        }
        __syncthreads();
        int nblk = n0 >> 6;
        #pragma unroll
        for (int s = 0; s < 2; ++s) {
            int o = t + s * 256;
            int rn = o & 63, ko = o >> 6;
            int kp = kp0 + ko * 8;
            int kt = kp >> 5, kc = (kp >> 3) & 3;
            f16 h8[8];
            #pragma unroll
            for (int e = 0; e < 8; ++e) h8[e] = (f16)lds[ko * 8 + e][rn];
            size_t off = ((size_t)(nblk * NKT + kt) * 4 + kc) * 512 + rn * 8;
            *(f16x8*)&T[off] = *(f16x8*)h8;
        }
    }
}

// ---------------- neighbors, wave per row ----------------
__global__ __launch_bounds__(256) void k_nbrs(const float* __restrict__ total_beta,
                                              const int* __restrict__ tasks,
                                              int* __restrict__ neighbors) {
    int wid = threadIdx.x >> 6, lane = threadIdx.x & 63;
    int row = blockIdx.x * 4 + wid;
    int bt = row / NAG, i = row - bt * NAG;
    int tk[MTOP];
    #pragma unroll
    for (int k = 0; k < MTOP; ++k) tk[k] = tasks[row * MTOP + k];
    float v1 = -INFINITY;
    if (lane < NAG) {
        const float* tba = total_beta + ((size_t)bt * NAG + lane) * MTASK;
        float mx = -INFINITY;
        #pragma unroll
        for (int k = 0; k < MTOP; ++k) mx = fmaxf(mx, tba[tk[k]]);
        v1 = (lane == i) ? -INFINITY : mx;
    }
    for (int k = 0; k < NNB; ++k) {
        float v = v1; int idx = lane;
        #pragma unroll
        for (int m = 1; m < 64; m <<= 1) {
            float vo = __shfl_xor(v, m, 64);
            int io = __shfl_xor(idx, m, 64);
            if (vo > v || (vo == v && io < idx)) { v = vo; idx = io; }
        }
        if (lane == 0) neighbors[row * NNB + k] = idx;
        if (idx == lane) v1 = -INFINITY;
    }
}

// ---------------- build inputs: LDS-staged gather, 8 rows/block, fp16 64-row tiled ----
__global__ __launch_bounds__(256) void k_build_inputs(
    const float* __restrict__ beta, const float* __restrict__ actions,
    const float* __restrict__ power, const int* __restrict__ prev,
    const int* __restrict__ tasks, const int* __restrict__ neighbors,
    f16* __restrict__ A) {
    int b = blockIdx.x;                 // rows [b*8, b*8+8)
    int t = threadIdx.x;
    __shared__ int tkv[8][MTOP], nbv[8][NNB], pav[8][NNB];
    __shared__ float pwv[8][NNB];
    __shared__ float fbuf[8][500];
    __shared__ float abuf[8][1004];
    if (t < 80) {
        int lr = t / 10, j = t - lr * 10;
        int row = b * 8 + lr;
        int bt = row / NAG;
        int nbj = neighbors[row * NNB + j];
        nbv[lr][j] = nbj;
        pav[lr][j] = prev[bt * NAG + nbj];
        pwv[lr][j] = power[bt * NAG + nbj];
        tkv[lr][j] = tasks[row * MTOP + j];
    }
    __syncthreads();
    int row0 = b * 8;
    #pragma unroll
    for (int it = 0; it < 4; ++it) {
        int idx = t + it * 256;
        if (idx < 800) {
            int l = idx / 100, p = idx - l * 100;
            int k = p / 10, j = p - k * 10;
            int row = row0 + l;
            int bt = row / NAG;
            const float* src = beta + ((size_t)(bt * NAG + nbv[l][j]) * MTASK
                                       + tkv[l][k]) * LDIM;
            int c0 = k * 50 + j * 5;
            #pragma unroll
            for (int i = 0; i < 5; ++i) fbuf[l][c0 + i] = src[i];
        }
    }
    #pragma unroll
    for (int it = 0; it < 8; ++it) {
        int idx = t + it * 256;
        if (idx < 2000) {
            int l = idx / 250, v = idx - l * 250;
            int j = v / 25, q = v - j * 25;
            int row = row0 + l;
            int bt = row / NAG;
            f32x4 a = *(const f32x4*)&actions[(size_t)(bt * NAG + nbv[l][j]) * MTASK + q * 4];
            *(f32x4*)&abuf[l][j * 100 + q * 4] = a;
        }
    }
    __syncthreads();
    int l = t & 7, og = t >> 3;
    int row = row0 + l;
    int rb = row >> 6, rlo = row & 63;
    #pragma unroll
    for (int s = 0; s < 7; ++s) {
        int o = og + 32 * s;
        if (o < 208) {                  // NKT1*4
            f16 h8[8];
            #pragma unroll
            for (int e = 0; e < 8; ++e) {
                int c = o * 8 + e;
                float f;
                if (c < 500) {
                    f = fbuf[l][c];
                } else if (c < 1500) {
                    f = abuf[l][c - 500];
                } else if (c < 1510) {
                    f = pwv[l][c - 1500];
                } else if (c < 1610) {
                    int r2 = c - 1510, k = r2 / NNB, j = r2 - k * NNB;
                    f = (tkv[l][k] == pav[l][j]) ? 1.f : 0.f;
                } else {
                    f = 0.f;
                }
                h8[e] = (f16)f;
            }
            size_t off = ((size_t)rb * 208 + o) * 512 + rlo * 8;
            *(f16x8*)&A[off] = *(f16x8*)h8;
        }
    }
}

// ---------------- fp16 MFMA GEMM, 64x128 tile, BK=32, A-reg, depth-2 pipeline ------
// Grid 800 = 200 mt x 4 nt, XCD-bijective swizzle. B staged via global_load_lds into
// 3 LDS buffers, prefetch distance 2, counted `s_waitcnt vmcnt(2)` + raw s_barrier
// (never drains the in-flight prefetch). A-frags global->VGPR, software-pipelined.
// Invariants: stage(k) drained one step before its barrier (vmcnt(2) leaves only the
// 2 newest ops, stage(k+1) is always older); buf (k+2)%3 overwrite is ordered after
// all B(k-1) reads by the barrier.
// MODE 0: epilogue = +bias, relu, fp16 64-row tiled write (feeds GEMM2).
// MODE 1: epilogue = +bias, relu, W3-slice dot (W3 in LDS) -> qpart[nt].
template<int NKT, int MODE>
__global__ __launch_bounds__(256, 4) void k_gemm(
    const f16* __restrict__ Ap, const f16* __restrict__ Bp,
    const float* __restrict__ bias, f16* __restrict__ C,
    const float* __restrict__ W3, float* __restrict__ qpart) {
    constexpr int SMEM = (MODE == 0) ? 34048 : 39680;   // >= 3x8KB bufs; sE 64x133 fp32 (+ W3s)
    __shared__ __align__(16) char smem[SMEM];
    f16* sB = (f16*)smem;                    // 3 bufs x 4096 f16 (24 KB)
    int tid = threadIdx.x, wid = tid >> 6, lane = tid & 63;
    int id = blockIdx.x;
    int swz = (id & 7) * 100 + (id >> 3);    // bijective: 800 % 8 == 0
    int nt = swz & 3, mt = swz >> 2;         // mt in [0,200)

    auto stage = [&](int kk, int buf) {
        #pragma unroll
        for (int j = 0; j < 2; ++j) {
            int seg = wid + 4 * j;           // 0..7
            int q = seg >> 2, kc = seg & 3;
            gload16(Bp + ((size_t)((2 * nt + q) * NKT + kk) * 4 + kc) * 512 + lane * 8,
                    sB + buf * 4096 + (kc * 128 + q * 64) * 8);
        }
    };

    int wr = wid >> 1, wc = wid & 1;         // wave-tile 32 rows x 64 cols
    int lrow = lane & 15, lk = lane >> 4;
    f32x4 acc[2][4] = {};

    auto aaddr = [&](int kk) {
        return ((size_t)(mt * NKT + kk) * 4 + lk) * 512 + (wr * 32 + lrow) * 8;
    };

    stage(0, 0);
    size_t ab0 = aaddr(0);
    f16x8 aCur0 = *(const f16x8*)(Ap + ab0);
    f16x8 aCur1 = *(const f16x8*)(Ap + ab0 + 128);
    stage(1, 1);
    for (int kk = 0; kk < NKT; ++kk) {
        // counted wait: keep the 2 newest vmem ops (deepest prefetch) in flight
        asm volatile("s_waitcnt vmcnt(2)" ::: "memory");
        __builtin_amdgcn_s_barrier();
        __builtin_amdgcn_sched_barrier(0);
        if (kk + 2 < NKT) stage(kk + 2, (kk + 2) % 3);
        // software-pipelined A fragment for next step
        int kn = (kk + 1 < NKT) ? kk + 1 : kk;
        size_t abn = aaddr(kn);
        f16x8 aN0 = *(const f16x8*)(Ap + abn);
        f16x8 aN1 = *(const f16x8*)(Ap + abn + 128);
        const f16* bb = sB + (kk % 3) * 4096;
        f16x8 bh[4];
        #pragma unroll
        for (int j = 0; j < 4; ++j)
            bh[j] = *(const f16x8*)(bb + (lk * 128 + wc * 64 + j * 16 + lrow) * 8);
        #pragma unroll
        for (int j = 0; j < 4; ++j) {
            acc[0][j] = __builtin_amdgcn_mfma_f32_16x16x32_f16(aCur0, bh[j], acc[0][j], 0, 0, 0);
            acc[1][j] = __builtin_amdgcn_mfma_f32_16x16x32_f16(aCur1, bh[j], acc[1][j], 0, 0, 0);
        }
        aCur0 = aN0;
        aCur1 = aN1;
    }

    // transpose acc into sE[64][133] (staging dead after this barrier)
    __syncthreads();
    float* sE = (float*)smem;
    #pragma unroll
    for (int i = 0; i < 2; ++i)
        #pragma unroll
        for (int j = 0; j < 4; ++j)
            #pragma unroll
            for (int r = 0; r < 4; ++r)
                sE[(wr * 32 + i * 16 + lk * 4 + r) * 133 + wc * 64 + j * 16 + lrow] = acc[i][j][r];

    if constexpr (MODE == 0) {
        __syncthreads();
        int l2 = tid & 63, og2 = tid >> 6;   // row, octet-group
        #pragma unroll
        for (int s2 = 0; s2 < 4; ++s2) {
            int o = og2 + 4 * s2;            // 0..15 local octet
            int n0 = nt * 128 + o * 8;
            f32x4 v0 = *(f32x4*)&sE[l2 * 133 + o * 8];
            f32x4 v1 = *(f32x4*)&sE[l2 * 133 + o * 8 + 4];
            f32x4 bb0 = *(const f32x4*)&bias[n0];
            f32x4 bb1 = *(const f32x4*)&bias[n0 + 4];
            f16 h8[8];
            #pragma unroll
            for (int i = 0; i < 4; ++i) {
                h8[i] = (f16)fmaxf(v0[i] + bb0[i], 0.f);
                h8[4 + i] = (f16)fmaxf(v1[i] + bb1[i], 0.f);
            }
            size_t off = ((size_t)mt * 64 + nt * 16 + o) * 512 + l2 * 8;
            *(f16x8*)&C[off] = *(f16x8*)h8;
        }
    } else {
        // stage W3 slice (128 x 11 = 5.6 KB) into LDS, coalesced
        float* W3s = (float*)(smem + 34048);
        for (int i = tid; i < 128 * NOUT; i += 256)
            W3s[i] = W3[nt * 128 * NOUT + i];
        __syncthreads();
        int row = tid >> 2, seg = tid & 3;   // 4 threads per row, 32 cols each
        float a11[NOUT];
        #pragma unroll
        for (int n = 0; n < NOUT; ++n) a11[n] = 0.f;
        #pragma unroll
        for (int c32 = 0; c32 < 32; ++c32) {
            int col = seg + 4 * c32;
            float h = fmaxf(sE[row * 133 + col] + bias[nt * 128 + col], 0.f);
            const float* w = W3s + col * NOUT;
            #pragma unroll
            for (int n = 0; n < NOUT; ++n) a11[n] += h * w[n];
        }
        #pragma unroll
        for (int d = 2; d >= 1; d >>= 1)
            #pragma unroll
            for (int n = 0; n < NOUT; ++n) a11[n] += __shfl_down(a11[n], d, 64);
        if (seg == 0) {
            int grow = mt * 64 + row;
            #pragma unroll
            for (int n = 0; n < NOUT; ++n)
                qpart[(size_t)nt * NROWS * NOUT + (size_t)grow * NOUT + n] = a11[n];
        }
    }
}

// ---------------- reduce 4 q-partials + b3 ----------------
__global__ __launch_bounds__(256) void k_qreduce(const float* __restrict__ qp,
                                                 const float* __restrict__ b3,
                                                 float* __restrict__ out) {
    int i = blockIdx.x * 256 + threadIdx.x;
    if (i < NROWS * NOUT) {
        int n = i % NOUT;
        const size_t P = (size_t)NROWS * NOUT;
        out[i] = b3[n] + qp[i] + qp[i + P] + qp[i + 2 * P] + qp[i + 3 * P];
    }
}

extern "C" void kernel_launch(void* const* d_in, const int* in_sizes, int n_in,
                              void* d_out, int out_size, void* d_ws, size_t ws_size,
                              hipStream_t stream) {
    const float* beta    = (const float*)d_in[0];
    const float* actions = (const float*)d_in[1];
    const float* power   = (const float*)d_in[2];
    const int*   prev    = (const int*)d_in[3];
    const float* W1      = (const float*)d_in[4];
    const float* b1      = (const float*)d_in[5];
    const float* W2      = (const float*)d_in[6];
    const float* b2      = (const float*)d_in[7];
    const float* W3      = (const float*)d_in[8];
    const float* b3      = (const float*)d_in[9];
    float* out = (float*)d_out;

    char* ws = (char*)d_ws;
    size_t off = 0;
    auto alloc = [&](size_t bytes) { void* p = ws + off; off += (bytes + 255) & ~(size_t)255; return p; };
    float* total_beta = (float*)alloc((size_t)NROWS * MTASK * 4);
    int*   tasks      = (int*)  alloc((size_t)NROWS * MTOP * 4);
    int*   neighbors  = (int*)  alloc((size_t)NROWS * NNB * 4);
    f16*   A    = (f16*)alloc((size_t)NROWS * KP1 * 2);
    f16*   W1t  = (f16*)alloc((size_t)HDIM * KP1 * 2);
    f16*   W2t  = (f16*)alloc((size_t)HDIM * HDIM * 2);
    f16*   h1   = (f16*)alloc((size_t)NROWS * HDIM * 2);
    float* qpart = (float*)alloc((size_t)4 * NROWS * NOUT * 4);

    // topk (3200 blocks) + weight prep (272 blocks), independent work
    k_topk_prep<<<NTOPKB + NPREPB, 256, 0, stream>>>(beta, total_beta, tasks,
                                                     W1, W2, W1t, W2t);
    k_nbrs<<<NROWS / 4, 256, 0, stream>>>(total_beta, tasks, neighbors);
    k_build_inputs<<<NROWS / 8, 256, 0, stream>>>(beta, actions, power, prev, tasks,
                                                  neighbors, A);
    // GEMM1: 64x128 tile, grid 800, fused b1+relu -> h1 (fp16 tiled)
    k_gemm<NKT1, 0><<<800, 256, 0, stream>>>(A, W1t, b1, h1, nullptr, nullptr);
    // GEMM2: 64x128 tile, grid 800, fused b2+relu+W3-slice dot -> qpart
    k_gemm<NKT2, 1><<<800, 256, 0, stream>>>(h1, W2t, b2, nullptr, W3, qpart);
    k_qreduce<<<(NROWS * NOUT + 255) / 256, 256, 0, stream>>>(qpart, b3, out);
}

// Round 20
// 141.736 us; speedup vs baseline: 1.0021x; 1.0021x over previous
//
#include <hip/hip_runtime.h>
#include <math.h>

#define NB 8
#define NT 32
#define NAG 50
#define MTASK 100
#define MTOP 10
#define NNB 10
#define LDIM 5
#define HDIM 512
#define INDIM 1610
#define KP1 1664            // INDIM padded to multiple of 64
#define NKT1 (KP1/32)       // 52 k-chunks
#define NKT2 (HDIM/32)      // 16
#define NROWS (NB*NT*NAG)   // 12800
#define NOUT (MTOP+1)       // 11
#define NTOPKB (NROWS/4)    // 3200 topk blocks
#define NPREPX (KP1/64 + HDIM/64)   // 34
#define NPREPB (NPREPX * (HDIM/64)) // 272 prep blocks

typedef float f32x4 __attribute__((ext_vector_type(4)));
typedef _Float16 f16;
typedef _Float16 f16x8 __attribute__((ext_vector_type(8)));

__device__ __forceinline__ void gload16(const void* g, void* l) {
    __builtin_amdgcn_global_load_lds(
        (__attribute__((address_space(1))) void*)(g),
        (__attribute__((address_space(3))) void*)(l), 16, 0, 0);
}

// A-side tiled layout (64-row blocks): elem (row, c) at
//   (rowblk64 * NKT*4 + octet)*512 + (row&63)*8 + (c&7),  octet = c>>3
// B-side tiled layout (64-col blocks): (colblk64 * NKT*4 + octet)*512 + (col&63)*8 + e.

// ---------------- merged: top-10 tasks (blocks 0..3199) + weight prep (3200..3471) ----
__global__ __launch_bounds__(256) void k_topk_prep(
    const float* __restrict__ beta, float* __restrict__ total_beta,
    int* __restrict__ tasks,
    const float* __restrict__ W1, const float* __restrict__ W2,
    f16* __restrict__ T1, f16* __restrict__ T2) {
    __shared__ float lds[64][65];
    if (blockIdx.x < NTOPKB) {
        // ---- topk: wave per row ----
        int wid = threadIdx.x >> 6, lane = threadIdx.x & 63;
        int row = blockIdx.x * 4 + wid;
        const float* bp = beta + (size_t)row * MTASK * LDIM;
        float v1, v2 = -INFINITY;
        {
            const float* p = bp + lane * LDIM;
            v1 = p[0] + p[1] + p[2] + p[3] + p[4];
            total_beta[(size_t)row * MTASK + lane] = v1;
        }
        if (lane + 64 < MTASK) {
            const float* p = bp + (lane + 64) * LDIM;
            v2 = p[0] + p[1] + p[2] + p[3] + p[4];
            total_beta[(size_t)row * MTASK + lane + 64] = v2;
        }
        for (int k = 0; k < MTOP; ++k) {
            float v; int idx;
            if (v1 >= v2) { v = v1; idx = lane; } else { v = v2; idx = lane + 64; }
            #pragma unroll
            for (int m = 1; m < 64; m <<= 1) {
                float vo = __shfl_xor(v, m, 64);
                int io = __shfl_xor(idx, m, 64);
                if (vo > v || (vo == v && io < idx)) { v = vo; idx = io; }
            }
            if (lane == 0) tasks[row * MTOP + k] = idx;
            if (idx == lane) v1 = -INFINITY;
            else if (idx == lane + 64) v2 = -INFINITY;
        }
    } else {
        // ---- weight prep: W[K][N] -> tiled fp16 (64-col blocks) ----
        int pb = blockIdx.x - NTOPKB;
        int bx = pb % NPREPX, n0 = (pb / NPREPX) * 64;
        const float* W; f16* T; int K, NKT, kp0;
        if (bx < KP1 / 64) { W = W1; T = T1; K = INDIM; NKT = NKT1; kp0 = bx * 64; }
        else               { W = W2; T = T2; K = HDIM;  NKT = NKT2; kp0 = (bx - KP1 / 64) * 64; }
        int t = threadIdx.x;
        int cc = t & 63, r0 = t >> 6;
        #pragma unroll
        for (int i = 0; i < 16; ++i) {
            int rr = r0 + i * 4;
            int kp = kp0 + rr;
            lds[rr][cc] = (kp < K) ? W[(size_t)kp * HDIM + n0 + cc] : 0.f;
        }
        __syncthreads();
        int nblk = n0 >> 6;
        #pragma unroll
        for (int s = 0; s < 2; ++s) {
            int o = t + s * 256;
            int rn = o & 63, ko = o >> 6;
            int kp = kp0 + ko * 8;
            int kt = kp >> 5, kc = (kp >> 3) & 3;
            f16 h8[8];
            #pragma unroll
            for (int e = 0; e < 8; ++e) h8[e] = (f16)lds[ko * 8 + e][rn];
            size_t off = ((size_t)(nblk * NKT + kt) * 4 + kc) * 512 + rn * 8;
            *(f16x8*)&T[off] = *(f16x8*)h8;
        }
    }
}

// ---------------- neighbors, wave per row ----------------
__global__ __launch_bounds__(256) void k_nbrs(const float* __restrict__ total_beta,
                                              const int* __restrict__ tasks,
                                              int* __restrict__ neighbors) {
    int wid = threadIdx.x >> 6, lane = threadIdx.x & 63;
    int row = blockIdx.x * 4 + wid;
    int bt = row / NAG, i = row - bt * NAG;
    int tk[MTOP];
    #pragma unroll
    for (int k = 0; k < MTOP; ++k) tk[k] = tasks[row * MTOP + k];
    float v1 = -INFINITY;
    if (lane < NAG) {
        const float* tba = total_beta + ((size_t)bt * NAG + lane) * MTASK;
        float mx = -INFINITY;
        #pragma unroll
        for (int k = 0; k < MTOP; ++k) mx = fmaxf(mx, tba[tk[k]]);
        v1 = (lane == i) ? -INFINITY : mx;
    }
    for (int k = 0; k < NNB; ++k) {
        float v = v1; int idx = lane;
        #pragma unroll
        for (int m = 1; m < 64; m <<= 1) {
            float vo = __shfl_xor(v, m, 64);
            int io = __shfl_xor(idx, m, 64);
            if (vo > v || (vo == v && io < idx)) { v = vo; idx = io; }
        }
        if (lane == 0) neighbors[row * NNB + k] = idx;
        if (idx == lane) v1 = -INFINITY;
    }
}

// ---------------- build inputs: LDS-staged gather, 8 rows/block, fp16 64-row tiled ----
__global__ __launch_bounds__(256) void k_build_inputs(
    const float* __restrict__ beta, const float* __restrict__ actions,
    const float* __restrict__ power, const int* __restrict__ prev,
    const int* __restrict__ tasks, const int* __restrict__ neighbors,
    f16* __restrict__ A) {
    int b = blockIdx.x;                 // rows [b*8, b*8+8)
    int t = threadIdx.x;
    __shared__ int tkv[8][MTOP], nbv[8][NNB], pav[8][NNB];
    __shared__ float pwv[8][NNB];
    __shared__ float fbuf[8][500];
    __shared__ float abuf[8][1004];
    if (t < 80) {
        int lr = t / 10, j = t - lr * 10;
        int row = b * 8 + lr;
        int bt = row / NAG;
        int nbj = neighbors[row * NNB + j];
        nbv[lr][j] = nbj;
        pav[lr][j] = prev[bt * NAG + nbj];
        pwv[lr][j] = power[bt * NAG + nbj];
        tkv[lr][j] = tasks[row * MTOP + j];
    }
    __syncthreads();
    int row0 = b * 8;
    #pragma unroll
    for (int it = 0; it < 4; ++it) {
        int idx = t + it * 256;
        if (idx < 800) {
            int l = idx / 100, p = idx - l * 100;
            int k = p / 10, j = p - k * 10;
            int row = row0 + l;
            int bt = row / NAG;
            const float* src = beta + ((size_t)(bt * NAG + nbv[l][j]) * MTASK
                                       + tkv[l][k]) * LDIM;
            int c0 = k * 50 + j * 5;
            #pragma unroll
            for (int i = 0; i < 5; ++i) fbuf[l][c0 + i] = src[i];
        }
    }
    #pragma unroll
    for (int it = 0; it < 8; ++it) {
        int idx = t + it * 256;
        if (idx < 2000) {
            int l = idx / 250, v = idx - l * 250;
            int j = v / 25, q = v - j * 25;
            int row = row0 + l;
            int bt = row / NAG;
            f32x4 a = *(const f32x4*)&actions[(size_t)(bt * NAG + nbv[l][j]) * MTASK + q * 4];
            *(f32x4*)&abuf[l][j * 100 + q * 4] = a;
        }
    }
    __syncthreads();
    int l = t & 7, og = t >> 3;
    int row = row0 + l;
    int rb = row >> 6, rlo = row & 63;
    #pragma unroll
    for (int s = 0; s < 7; ++s) {
        int o = og + 32 * s;
        if (o < 208) {                  // NKT1*4
            f16 h8[8];
            #pragma unroll
            for (int e = 0; e < 8; ++e) {
                int c = o * 8 + e;
                float f;
                if (c < 500) {
                    f = fbuf[l][c];
                } else if (c < 1500) {
                    f = abuf[l][c - 500];
                } else if (c < 1510) {
                    f = pwv[l][c - 1500];
                } else if (c < 1610) {
                    int r2 = c - 1510, k = r2 / NNB, j = r2 - k * NNB;
                    f = (tkv[l][k] == pav[l][j]) ? 1.f : 0.f;
                } else {
                    f = 0.f;
                }
                h8[e] = (f16)f;
            }
            size_t off = ((size_t)rb * 208 + o) * 512 + rlo * 8;
            *(f16x8*)&A[off] = *(f16x8*)h8;
        }
    }
}

// ---------------- fp16 MFMA GEMM, 64x128 tile, BK=32, A via register loads ----------------
// Grid 800 = 200 mt x 4 nt, XCD-bijective swizzle. LDS stages B only (16KB dbuf);
// A-frags load global->VGPR per wave (same (lane,e)->k map as the LDS path, so
// MFMA k-permutation cancels; wc-partner duplication is L2-absorbed).
// MODE 0: epilogue = +bias, relu, fp16 64-row tiled write (feeds GEMM2).
// MODE 1: epilogue = +bias, relu, W3-slice dot (W3 in LDS) -> qpart[nt].
template<int NKT, int MODE>
__global__ __launch_bounds__(256, 4) void k_gemm(
    const f16* __restrict__ Ap, const f16* __restrict__ Bp,
    const float* __restrict__ bias, f16* __restrict__ C,
    const float* __restrict__ W3, float* __restrict__ qpart) {
    constexpr int SMEM = (MODE == 0) ? 34048 : 39680;   // sE 64x133 fp32 (+ W3s)
    __shared__ __align__(16) char smem[SMEM];
    f16* sB = (f16*)smem;                    // 2 bufs x 4096 f16 (16 KB)
    int tid = threadIdx.x, wid = tid >> 6, lane = tid & 63;
    int id = blockIdx.x;
    int swz = (id & 7) * 100 + (id >> 3);    // bijective: 800 % 8 == 0
    int nt = swz & 3, mt = swz >> 2;         // mt in [0,200)

    auto stage = [&](int kk, int buf) {
        #pragma unroll
        for (int j = 0; j < 2; ++j) {
            int seg = wid + 4 * j;           // 0..7
            int q = seg >> 2, kc = seg & 3;
            gload16(Bp + ((size_t)((2 * nt + q) * NKT + kk) * 4 + kc) * 512 + lane * 8,
                    sB + buf * 4096 + (kc * 128 + q * 64) * 8);
        }
    };

    int wr = wid >> 1, wc = wid & 1;         // wave-tile 32 rows x 64 cols
    int lrow = lane & 15, lk = lane >> 4;
    f32x4 acc[2][4] = {};

    stage(0, 0);
    for (int kk = 0; kk < NKT; ++kk) {
        int buf = kk & 1;
        __syncthreads();
        // A-register loads first (oldest vmcnt entries -> counted wait before MFMA)
        size_t abase = ((size_t)(mt * NKT + kk) * 4 + lk) * 512 + (wr * 32 + lrow) * 8;
        f16x8 a0 = *(const f16x8*)(Ap + abase);
        f16x8 a1 = *(const f16x8*)(Ap + abase + 128);   // +16 rows
        if (kk + 1 < NKT) stage(kk + 1, buf ^ 1);
        f16x8 bh[4];
        #pragma unroll
        for (int j = 0; j < 4; ++j)
            bh[j] = *(const f16x8*)(sB + buf * 4096 + (lk * 128 + wc * 64 + j * 16 + lrow) * 8);
        #pragma unroll
        for (int j = 0; j < 4; ++j) {
            acc[0][j] = __builtin_amdgcn_mfma_f32_16x16x32_f16(a0, bh[j], acc[0][j], 0, 0, 0);
            acc[1][j] = __builtin_amdgcn_mfma_f32_16x16x32_f16(a1, bh[j], acc[1][j], 0, 0, 0);
        }
    }

    // transpose acc into sE[64][133] (staging dead after this barrier)
    __syncthreads();
    float* sE = (float*)smem;
    #pragma unroll
    for (int i = 0; i < 2; ++i)
        #pragma unroll
        for (int j = 0; j < 4; ++j)
            #pragma unroll
            for (int r = 0; r < 4; ++r)
                sE[(wr * 32 + i * 16 + lk * 4 + r) * 133 + wc * 64 + j * 16 + lrow] = acc[i][j][r];

    if constexpr (MODE == 0) {
        __syncthreads();
        int l2 = tid & 63, og2 = tid >> 6;   // row, octet-group
        #pragma unroll
        for (int s2 = 0; s2 < 4; ++s2) {
            int o = og2 + 4 * s2;            // 0..15 local octet
            int n0 = nt * 128 + o * 8;
            f32x4 v0 = *(f32x4*)&sE[l2 * 133 + o * 8];
            f32x4 v1 = *(f32x4*)&sE[l2 * 133 + o * 8 + 4];
            f32x4 bb0 = *(const f32x4*)&bias[n0];
            f32x4 bb1 = *(const f32x4*)&bias[n0 + 4];
            f16 h8[8];
            #pragma unroll
            for (int i = 0; i < 4; ++i) {
                h8[i] = (f16)fmaxf(v0[i] + bb0[i], 0.f);
                h8[4 + i] = (f16)fmaxf(v1[i] + bb1[i], 0.f);
            }
            size_t off = ((size_t)mt * 64 + nt * 16 + o) * 512 + l2 * 8;
            *(f16x8*)&C[off] = *(f16x8*)h8;
        }
    } else {
        // stage W3 slice (128 x 11 = 5.6 KB) into LDS, coalesced
        float* W3s = (float*)(smem + 34048);
        for (int i = tid; i < 128 * NOUT; i += 256)
            W3s[i] = W3[nt * 128 * NOUT + i];
        __syncthreads();
        int row = tid >> 2, seg = tid & 3;   // 4 threads per row, 32 cols each
        float a11[NOUT];
        #pragma unroll
        for (int n = 0; n < NOUT; ++n) a11[n] = 0.f;
        #pragma unroll
        for (int c32 = 0; c32 < 32; ++c32) {
            int col = seg + 4 * c32;
            float h = fmaxf(sE[row * 133 + col] + bias[nt * 128 + col], 0.f);
            const float* w = W3s + col * NOUT;
            #pragma unroll
            for (int n = 0; n < NOUT; ++n) a11[n] += h * w[n];
        }
        #pragma unroll
        for (int d = 2; d >= 1; d >>= 1)
            #pragma unroll
            for (int n = 0; n < NOUT; ++n) a11[n] += __shfl_down(a11[n], d, 64);
        if (seg == 0) {
            int grow = mt * 64 + row;
            #pragma unroll
            for (int n = 0; n < NOUT; ++n)
                qpart[(size_t)nt * NROWS * NOUT + (size_t)grow * NOUT + n] = a11[n];
        }
    }
}

// ---------------- reduce 4 q-partials + b3 ----------------
__global__ __launch_bounds__(256) void k_qreduce(const float* __restrict__ qp,
                                                 const float* __restrict__ b3,
                                                 float* __restrict__ out) {
    int i = blockIdx.x * 256 + threadIdx.x;
    if (i < NROWS * NOUT) {
        int n = i % NOUT;
        const size_t P = (size_t)NROWS * NOUT;
        out[i] = b3[n] + qp[i] + qp[i + P] + qp[i + 2 * P] + qp[i + 3 * P];
    }
}

extern "C" void kernel_launch(void* const* d_in, const int* in_sizes, int n_in,
                              void* d_out, int out_size, void* d_ws, size_t ws_size,
                              hipStream_t stream) {
    const float* beta    = (const float*)d_in[0];
    const float* actions = (const float*)d_in[1];
    const float* power   = (const float*)d_in[2];
    const int*   prev    = (const int*)d_in[3];
    const float* W1      = (const float*)d_in[4];
    const float* b1      = (const float*)d_in[5];
    const float* W2      = (const float*)d_in[6];
    const float* b2      = (const float*)d_in[7];
    const float* W3      = (const float*)d_in[8];
    const float* b3      = (const float*)d_in[9];
    float* out = (float*)d_out;

    char* ws = (char*)d_ws;
    size_t off = 0;
    auto alloc = [&](size_t bytes) { void* p = ws + off; off += (bytes + 255) & ~(size_t)255; return p; };
    float* total_beta = (float*)alloc((size_t)NROWS * MTASK * 4);
    int*   tasks      = (int*)  alloc((size_t)NROWS * MTOP * 4);
    int*   neighbors  = (int*)  alloc((size_t)NROWS * NNB * 4);
    f16*   A    = (f16*)alloc((size_t)NROWS * KP1 * 2);
    f16*   W1t  = (f16*)alloc((size_t)HDIM * KP1 * 2);
    f16*   W2t  = (f16*)alloc((size_t)HDIM * HDIM * 2);
    f16*   h1   = (f16*)alloc((size_t)NROWS * HDIM * 2);
    float* qpart = (float*)alloc((size_t)4 * NROWS * NOUT * 4);

    // topk (3200 blocks) + weight prep (272 blocks), independent work
    k_topk_prep<<<NTOPKB + NPREPB, 256, 0, stream>>>(beta, total_beta, tasks,
                                                     W1, W2, W1t, W2t);
    k_nbrs<<<NROWS / 4, 256, 0, stream>>>(total_beta, tasks, neighbors);
    k_build_inputs<<<NROWS / 8, 256, 0, stream>>>(beta, actions, power, prev, tasks,
                                                  neighbors, A);
    // GEMM1: 64x128 tile, grid 800, fused b1+relu -> h1 (fp16 tiled)
    k_gemm<NKT1, 0><<<800, 256, 0, stream>>>(A, W1t, b1, h1, nullptr, nullptr);
    // GEMM2: 64x128 tile, grid 800, fused b2+relu+W3-slice dot -> qpart
    k_gemm<NKT2, 1><<<800, 256, 0, stream>>>(h1, W2t, b2, nullptr, W3, qpart);
    k_qreduce<<<(NROWS * NOUT + 255) / 256, 256, 0, stream>>>(qpart, b3, out);
}